// Round 7
// baseline (247.994 us; speedup 1.0000x reference)
//
#include <hip/hip_runtime.h>

// VcpAtt: q = Wq@src_emb + bq ; k = Wk@tgt_emb + bk ;
// scores = softmax_m(2*q.k - ||k||^2)  (||q||^2 cancels in softmax)
// out = [src (copy), src_corr = tgt @ scores^T]
//
// fp16 hi/lo split (3-pass MFMA). Flash-fused S GEMM + online softmax + PV.
// Pipelined K-loop (counted vmcnt + raw s_barrier), deferred softmax bursts.
// R6: XCD-aware block swizzle (T1) — each (mc,b) K-chunk group pinned to one
// XCD so the shared K/tgt stream is L2-local (was 8x duplicated across XCDs).

typedef _Float16 f16;
typedef __attribute__((ext_vector_type(8))) _Float16 f16x8;
typedef __attribute__((ext_vector_type(4))) float f32x4;

constexpr int B_ = 2, E_ = 512, N_ = 4096, M_ = 4096;
constexpr int MCH = 8;               // m-chunks (512 cols each)
constexpr float WSCALE = 64.0f;

__device__ __forceinline__ f32x4 mfma16(f16x8 a, f16x8 b, f32x4 c) {
  return __builtin_amdgcn_mfma_f32_16x16x32_f16(a, b, c, 0, 0, 0);
}
__device__ __forceinline__ void gll16(const void* g, void* l) {
  __builtin_amdgcn_global_load_lds(
      (const __attribute__((address_space(1))) unsigned int*)g,
      (__attribute__((address_space(3))) unsigned int*)l, 16, 0, 0);
}
__device__ __forceinline__ void waitv8() { asm volatile("s_waitcnt vmcnt(8)" ::: "memory"); }
__device__ __forceinline__ void waitv0() { asm volatile("s_waitcnt vmcnt(0)" ::: "memory"); }
__device__ __forceinline__ f32x4 vmax4(f32x4 a, f32x4 b) {
  f32x4 r;
  r[0] = fmaxf(a[0], b[0]); r[1] = fmaxf(a[1], b[1]);
  r[2] = fmaxf(a[2], b[2]); r[3] = fmaxf(a[3], b[3]);
  return r;
}
__device__ __forceinline__ f32x4 vexp4(f32x4 a) {
  f32x4 r;
  r[0] = __expf(a[0]); r[1] = __expf(a[1]);
  r[2] = __expf(a[2]); r[3] = __expf(a[3]);
  return r;
}

// LDS tile: 128 rows x 128B. Row = 8 slots of 16B; logical slot q<4 = H
// elems [q*8,q*8+8) of the 32-wide K-block, q>=4 = L. Phys slot = q^(row&7).
// Staged linear-dest (global_load_lds) via inverse-swizzled global source.

// ---- split W into f16 hi/lo (scaled) ------------------------------------
__global__ void k_split_w(const float* __restrict__ Wq, const float* __restrict__ Wk,
                          f16* __restrict__ WqH, f16* __restrict__ WqL,
                          f16* __restrict__ WkH, f16* __restrict__ WkL) {
  int i = blockIdx.x * 256 + threadIdx.x;
  float a = Wq[i] * WSCALE;
  f16 ah = (f16)a; WqH[i] = ah; WqL[i] = (f16)(a - (float)ah);
  float b = Wk[i] * WSCALE;
  f16 bh = (f16)b; WkH[i] = bh; WkL[i] = (f16)(b - (float)bh);
}

// ---- transpose (E,N) fp32 -> (N,E) f16 hi/lo ----------------------------
__global__ void k_tsplit(const float* __restrict__ Xq, const float* __restrict__ Xk,
                         f16* __restrict__ XqH, f16* __restrict__ XqL,
                         f16* __restrict__ XkH, f16* __restrict__ XkL) {
  __shared__ float tile[64][65];
  const int b = blockIdx.z >> 1, which = blockIdx.z & 1;
  const float* X = (which ? Xk : Xq) + (size_t)b * E_ * N_;
  f16* H = (which ? XkH : XqH) + (size_t)b * N_ * E_;
  f16* L = (which ? XkL : XqL) + (size_t)b * N_ * E_;
  const int e0 = blockIdx.x * 64, n0 = blockIdx.y * 64;
  const int x = threadIdx.x, y = threadIdx.y;
#pragma unroll
  for (int j = 0; j < 16; ++j) {
    int e = y * 16 + j;
    tile[e][x] = X[(size_t)(e0 + e) * N_ + n0 + x];
  }
  __syncthreads();
#pragma unroll
  for (int j = 0; j < 16; ++j) {
    int nl = y * 16 + j;
    float v = tile[x][nl];
    f16 h = (f16)v;
    H[(size_t)(n0 + nl) * E_ + e0 + x] = h;
    L[(size_t)(n0 + nl) * E_ + e0 + x] = (f16)(v - (float)h);
  }
}

// ---- projection GEMM (pipelined 2x2-wave 128x128), kk fused, XCD-swz ----
__global__ __launch_bounds__(256, 2) void k_proj(
    const f16* __restrict__ XqH, const f16* __restrict__ XqL,
    const f16* __restrict__ XkH, const f16* __restrict__ XkL,
    const f16* __restrict__ WqH, const f16* __restrict__ WqL,
    const f16* __restrict__ WkH, const f16* __restrict__ WkL,
    const float* __restrict__ bq, const float* __restrict__ bk,
    f16* __restrict__ QH, f16* __restrict__ QL,
    f16* __restrict__ KH, f16* __restrict__ KL,
    float* __restrict__ kkout) {
  __shared__ char lds[65536];   // A:[2]x16K @0, B:[2]x16K @32768
  // XCD swizzle: 512 blocks -> 8 groups of 64 keyed by (f-tile, kind);
  // group g lives on XCD g, so the shared W-tile (256KB) is L2-resident.
  const int flat = blockIdx.x + 32 * (blockIdx.y + 4 * blockIdx.z);
  const int rx = flat & 7, jx = flat >> 3;          // 8 x 64
  const int kind = rx & 1;
  const int f0 = (rx >> 1) * 128;
  const int n0 = (jx & 31) * 128;
  const int b  = jx >> 5;

  const f16* AH = (kind ? XkH : XqH) + (size_t)b * N_ * E_;
  const f16* AL = (kind ? XkL : XqL) + (size_t)b * N_ * E_;
  const f16* BH = kind ? WkH : WqH;
  const f16* BL = kind ? WkL : WqL;
  const float* bias = kind ? bk : bq;
  f16* OH = (kind ? KH : QH) + (size_t)b * N_ * E_;
  f16* OL = (kind ? KL : QL) + (size_t)b * N_ * E_;
  const int l = threadIdx.x & 63, w = threadIdx.x >> 6;
  const int wr = (w >> 1) * 64, wc = (w & 1) * 64;
  const int r15 = l & 15;

  const int q = (l & 7) ^ (l >> 3);
  const size_t soff = (size_t)(w * 8 + (l >> 3)) * E_ + (q & 3) * 8;
  const f16* sA = (q < 4 ? AH : AL) + (size_t)n0 * E_ + soff;
  const f16* sB = (q < 4 ? BH : BL) + (size_t)f0 * E_ + soff;

  auto STAGE = [&](int k) {
    char* dA = lds + ((k & 1) << 14) + w * 1024;
    char* dB = lds + 32768 + ((k & 1) << 14) + w * 1024;
    const f16* pa = sA + k * 32;
    const f16* pb = sB + k * 32;
#pragma unroll
    for (int c = 0; c < 4; ++c) {
      gll16(pa + (size_t)c * 32 * E_, dA + c * 4096);
      gll16(pb + (size_t)c * 32 * E_, dB + c * 4096);
    }
  };

  const int pH16 = ((l >> 4) ^ (l & 7)) * 16;
  const int aoffH = (wr + r15) * 128 + pH16;
  const int boffH = (wc + r15) * 128 + pH16;

  f32x4 acc[4][4] = {};
  STAGE(0);
#pragma unroll 2
  for (int k = 0; k < 16; ++k) {
    if (k < 15) { STAGE(k + 1); waitv8(); } else { waitv0(); }
    __builtin_amdgcn_sched_barrier(0);
    __builtin_amdgcn_s_barrier();
    const char* cA = lds + ((k & 1) << 14);
    const char* cB = lds + 32768 + ((k & 1) << 14);
    f16x8 ah[4], al[4], bh[4], bl[4];
#pragma unroll
    for (int i = 0; i < 4; ++i) {
      ah[i] = *(const f16x8*)(cA + aoffH + i * 2048);
      al[i] = *(const f16x8*)(cA + (aoffH ^ 64) + i * 2048);
      bh[i] = *(const f16x8*)(cB + boffH + i * 2048);
      bl[i] = *(const f16x8*)(cB + (boffH ^ 64) + i * 2048);
    }
    __builtin_amdgcn_s_setprio(1);
#pragma unroll
    for (int i = 0; i < 4; ++i)
#pragma unroll
      for (int j = 0; j < 4; ++j) {
        acc[i][j] = mfma16(ah[i], bh[j], acc[i][j]);
        acc[i][j] = mfma16(ah[i], bl[j], acc[i][j]);
        acc[i][j] = mfma16(al[i], bh[j], acc[i][j]);
      }
    __builtin_amdgcn_s_setprio(0);
    __builtin_amdgcn_s_barrier();
  }

  const int rowg = (l >> 4) * 4;
  float kkp[4][4];
#pragma unroll
  for (int i = 0; i < 4; ++i)
#pragma unroll
    for (int r = 0; r < 4; ++r) kkp[i][r] = 0.f;
#pragma unroll
  for (int j = 0; j < 4; ++j) {
    int f = f0 + wc + j * 16 + r15;
    float bv = bias[f];
#pragma unroll
    for (int i = 0; i < 4; ++i) {
#pragma unroll
      for (int r = 0; r < 4; ++r) {
        int n = n0 + wr + i * 16 + rowg + r;
        float qv = acc[i][j][r] * (1.0f / WSCALE) + bv;
        f16 h = (f16)qv;
        OH[(size_t)n * E_ + f] = h;
        OL[(size_t)n * E_ + f] = (f16)(qv - (float)h);
        kkp[i][r] += qv * qv;
      }
    }
  }
  if (kind) {
#pragma unroll
    for (int i = 0; i < 4; ++i)
#pragma unroll
      for (int r = 0; r < 4; ++r) {
        float v = kkp[i][r];
        v += __shfl_xor(v, 1); v += __shfl_xor(v, 2);
        v += __shfl_xor(v, 4); v += __shfl_xor(v, 8);
        if (r15 == 0) {
          int n = n0 + wr + i * 16 + rowg + r;
          atomicAdd(&kkout[(size_t)b * M_ + n], v);
        }
      }
  }
}

// ---- flash: pipelined S GEMM + deferred softmax + PV over one m-chunk ---
// grid 512 blocks; XCD-swz: group (mc,b) -> XCD (flat&7), 32 n-blocks each.
__global__ __launch_bounds__(256, 2) void k_flash(
    const f16* __restrict__ QH, const f16* __restrict__ QL,
    const f16* __restrict__ KH, const f16* __restrict__ KL,
    const float* __restrict__ kk, const float* __restrict__ tgt,
    float* __restrict__ part) {
  __shared__ char lds[73728];   // A:[2]x16K @0, B:[2]x16K @32768, ksw @65536
  float* ksw = (float*)(lds + 65536);  // [4][16][8] x {kk,t0,t1,t2} (8KB)
  // XCD swizzle: 16 groups keyed by (mc,b); XCD r hosts groups 2r, 2r+1.
  const int flat = blockIdx.x + 32 * (blockIdx.y + MCH * blockIdx.z);
  const int rx = flat & 7, jx = flat >> 3;          // 8 x 64
  const int grp = rx * 2 + (jx >> 5);               // 0..15
  const int n0 = (jx & 31) * 128;
  const int b  = grp & 1;
  const int mc = grp >> 1, m0c = mc * 512;
  const int tid = threadIdx.x, l = tid & 63, w = tid >> 6;
  const int r15 = l & 15;

  for (int idx = tid; idx < 512; idx += 256) {
    int mt = idx >> 7, rem = idx & 127, j = rem >> 4, rr = rem & 15;
    int dst = (mt * 16 + rr) * 8 + j;
    ksw[dst]        = kk[(size_t)b * M_ + m0c + idx];
    ksw[512 + dst]  = tgt[((size_t)b * 3 + 0) * M_ + m0c + idx];
    ksw[1024 + dst] = tgt[((size_t)b * 3 + 1) * M_ + m0c + idx];
    ksw[1536 + dst] = tgt[((size_t)b * 3 + 2) * M_ + m0c + idx];
  }
  __syncthreads();

  const f16* AH = QH + ((size_t)b * N_ + n0) * E_;
  const f16* AL = QL + ((size_t)b * N_ + n0) * E_;
  const f16* BHb = KH + ((size_t)b * M_ + m0c) * E_;
  const f16* BLb = KL + ((size_t)b * M_ + m0c) * E_;

  const int q = (l & 7) ^ (l >> 3);
  const size_t soff = (size_t)(w * 8 + (l >> 3)) * E_ + (q & 3) * 8;
  const f16* sA = (q < 4 ? AH : AL) + soff;
  const f16* sB = (q < 4 ? BHb : BLb) + soff;

  auto STAGE = [&](int s) {
    int mt_ = s >> 4, k_ = s & 15;
    char* dA = lds + ((s & 1) << 14) + w * 1024;
    char* dB = lds + 32768 + ((s & 1) << 14) + w * 1024;
    const f16* pa = sA + k_ * 32;
    const f16* pb = sB + (size_t)mt_ * 128 * E_ + k_ * 32;
#pragma unroll
    for (int c = 0; c < 4; ++c) {
      gll16(pa + (size_t)c * 32 * E_, dA + c * 4096);
      gll16(pb + (size_t)c * 32 * E_, dB + c * 4096);
    }
  };

  const int pH16 = ((l >> 4) ^ (l & 7)) * 16;
  const int aoffH = (w * 32 + r15) * 128 + pH16;
  const int boffH = r15 * 128 + pH16;

  f32x4 mrunA = {-3.0e38f, -3.0e38f, -3.0e38f, -3.0e38f};
  f32x4 mrunB = {-3.0e38f, -3.0e38f, -3.0e38f, -3.0e38f};
  f32x4 psumA = {}, p0A = {}, p1A = {}, p2A = {};
  f32x4 psumB = {}, p0B = {}, p1B = {}, p2B = {};

  auto BURST = [&](const f32x4 (&aP)[2][8], int i01, int pmt,
                   f32x4& mrun, f32x4& psum, f32x4& p0, f32x4& p1, f32x4& p2)
      __attribute__((always_inline)) {
    const float* bp = ksw + (pmt * 16 + r15) * 8;
    f32x4 kvL = *(const f32x4*)(bp);
    f32x4 kvH = *(const f32x4*)(bp + 4);
    f32x4 t0L = *(const f32x4*)(bp + 512),  t0H = *(const f32x4*)(bp + 516);
    f32x4 t1L = *(const f32x4*)(bp + 1024), t1H = *(const f32x4*)(bp + 1028);
    f32x4 t2L = *(const f32x4*)(bp + 1536), t2H = *(const f32x4*)(bp + 1540);
    float kv[8]  = {kvL[0], kvL[1], kvL[2], kvL[3], kvH[0], kvH[1], kvH[2], kvH[3]};
    float tv0[8] = {t0L[0], t0L[1], t0L[2], t0L[3], t0H[0], t0H[1], t0H[2], t0H[3]};
    float tv1[8] = {t1L[0], t1L[1], t1L[2], t1L[3], t1H[0], t1H[1], t1H[2], t1H[3]};
    float tv2[8] = {t2L[0], t2L[1], t2L[2], t2L[3], t2H[0], t2H[1], t2H[2], t2H[3]};
    f32x4 sv[8];
    f32x4 mx = {-3.0e38f, -3.0e38f, -3.0e38f, -3.0e38f};
#pragma unroll
    for (int j = 0; j < 8; ++j) {
      sv[j] = 2.0f * aP[i01][j] - kv[j];
      mx = vmax4(mx, sv[j]);
    }
#pragma unroll
    for (int e = 0; e < 4; ++e) {
      float v = mx[e];
      v = fmaxf(v, __shfl_xor(v, 1)); v = fmaxf(v, __shfl_xor(v, 2));
      v = fmaxf(v, __shfl_xor(v, 4)); v = fmaxf(v, __shfl_xor(v, 8));
      mx[e] = v;
    }
    f32x4 nm = vmax4(mrun, mx);
    f32x4 sc = vexp4(mrun - nm);
    mrun = nm;
    psum *= sc; p0 *= sc; p1 *= sc; p2 *= sc;
#pragma unroll
    for (int j = 0; j < 8; ++j) {
      f32x4 e4 = vexp4(sv[j] - nm);
      psum += e4;
      p0 += e4 * tv0[j];
      p1 += e4 * tv1[j];
      p2 += e4 * tv2[j];
    }
  };

  auto TILE = [&](int mt, f32x4 (&acc)[2][8], const f32x4 (&aP)[2][8], bool doSM)
      __attribute__((always_inline)) {
#pragma unroll
    for (int i = 0; i < 2; ++i)
#pragma unroll
      for (int j = 0; j < 8; ++j) acc[i][j] = f32x4{0.f, 0.f, 0.f, 0.f};
#pragma unroll 2
    for (int k = 0; k < 16; ++k) {
      const int s = mt * 16 + k;
      if (s < 63) { STAGE(s + 1); waitv8(); } else { waitv0(); }
      __builtin_amdgcn_sched_barrier(0);
      __builtin_amdgcn_s_barrier();
      const char* cA = lds + ((s & 1) << 14);
      const char* cB = lds + 32768 + ((s & 1) << 14);
      f16x8 ah0 = *(const f16x8*)(cA + aoffH);
      f16x8 ah1 = *(const f16x8*)(cA + aoffH + 2048);
      f16x8 al0 = *(const f16x8*)(cA + (aoffH ^ 64));
      f16x8 al1 = *(const f16x8*)(cA + (aoffH ^ 64) + 2048);
      __builtin_amdgcn_s_setprio(1);
#pragma unroll
      for (int j = 0; j < 8; ++j) {
        f16x8 bh = *(const f16x8*)(cB + boffH + j * 2048);
        f16x8 bl = *(const f16x8*)(cB + (boffH ^ 64) + j * 2048);
        acc[0][j] = mfma16(ah0, bh, acc[0][j]);
        acc[1][j] = mfma16(ah1, bh, acc[1][j]);
        acc[0][j] = mfma16(ah0, bl, acc[0][j]);
        acc[1][j] = mfma16(ah1, bl, acc[1][j]);
        acc[0][j] = mfma16(al0, bh, acc[0][j]);
        acc[1][j] = mfma16(al1, bh, acc[1][j]);
      }
      __builtin_amdgcn_s_setprio(0);
      __builtin_amdgcn_s_barrier();
      if (doSM && k == 7)  BURST(aP, 0, mt - 1, mrunA, psumA, p0A, p1A, p2A);
      if (doSM && k == 15) BURST(aP, 1, mt - 1, mrunB, psumB, p0B, p1B, p2B);
    }
  };

  f32x4 accE[2][8], accO[2][8];
  STAGE(0);
  TILE(0, accE, accO, false);
  TILE(1, accO, accE, true);
  TILE(2, accE, accO, true);
  TILE(3, accO, accE, true);
  BURST(accO, 0, 3, mrunA, psumA, p0A, p1A, p2A);
  BURST(accO, 1, 3, mrunB, psumB, p0B, p1B, p2B);

  auto RED = [&](f32x4& v) __attribute__((always_inline)) {
#pragma unroll
    for (int e = 0; e < 4; ++e) {
      float x = v[e];
      x += __shfl_xor(x, 1); x += __shfl_xor(x, 2);
      x += __shfl_xor(x, 4); x += __shfl_xor(x, 8);
      v[e] = x;
    }
  };
  RED(psumA); RED(p0A); RED(p1A); RED(p2A);
  RED(psumB); RED(p0B); RED(p1B); RED(p2B);

  if (r15 == 0) {
    const int hi = l >> 4;
#pragma unroll
    for (int i = 0; i < 2; ++i)
#pragma unroll
      for (int r = 0; r < 4; ++r) {
        int n = n0 + w * 32 + i * 16 + hi * 4 + r;
        size_t pb = ((size_t)(b * N_ + n) * MCH + mc) * 5;
        part[pb + 0] = i ? mrunB[r] : mrunA[r];
        part[pb + 1] = i ? psumB[r] : psumA[r];
        part[pb + 2] = i ? p0B[r] : p0A[r];
        part[pb + 3] = i ? p1B[r] : p1A[r];
        part[pb + 4] = i ? p2B[r] : p2A[r];
      }
  }
}

// ---- combine per-chunk partials -> output, plus src passthrough ---------
__global__ void k_out(const float* __restrict__ part, const float* __restrict__ src,
                      float* __restrict__ out) {
  int gid = blockIdx.x * 256 + threadIdx.x;
  if (blockIdx.x < B_ * N_ / 256) {           // combine: 8192 rows
    int idx = gid;                            // b*N + n
    int b = idx >> 12, n = idx & (N_ - 1);
    const float* p = part + (size_t)idx * MCH * 5;
    float M = -3.0e38f;
#pragma unroll
    for (int c = 0; c < MCH; ++c) M = fmaxf(M, p[c * 5]);
    float S = 0.f, P0 = 0.f, P1 = 0.f, P2 = 0.f;
#pragma unroll
    for (int c = 0; c < MCH; ++c) {
      float e = __expf(p[c * 5] - M);
      S += p[c * 5 + 1] * e;
      P0 += p[c * 5 + 2] * e;
      P1 += p[c * 5 + 3] * e;
      P2 += p[c * 5 + 4] * e;
    }
    float inv = 1.0f / S;
    float* oc = out + (size_t)B_ * 3 * N_;
    oc[((size_t)b * 3 + 0) * N_ + n] = P0 * inv;
    oc[((size_t)b * 3 + 1) * N_ + n] = P1 * inv;
    oc[((size_t)b * 3 + 2) * N_ + n] = P2 * inv;
  } else {                                    // src copy: 24576 elements
    int i = gid - B_ * N_;
    out[i] = src[i];
  }
}

extern "C" void kernel_launch(void* const* d_in, const int* in_sizes, int n_in,
                              void* d_out, int out_size, void* d_ws, size_t ws_size,
                              hipStream_t stream) {
  const float* src_emb = (const float*)d_in[0];
  const float* tgt_emb = (const float*)d_in[1];
  const float* src     = (const float*)d_in[2];
  const float* tgt     = (const float*)d_in[3];
  const float* Wq      = (const float*)d_in[4];
  const float* bq      = (const float*)d_in[5];
  const float* Wk      = (const float*)d_in[6];
  const float* bk      = (const float*)d_in[7];
  float* out = (float*)d_out;

  constexpr size_t SZX = (size_t)B_ * N_ * E_;
  constexpr size_t OFFW = 4 * SZX * sizeof(f16);
  constexpr size_t OFFQ = OFFW + 4 * (size_t)E_ * E_ * sizeof(f16);
  constexpr size_t OFFK2 = OFFQ + 4 * SZX * sizeof(f16);
  constexpr size_t OFFP = OFFK2 + (size_t)B_ * M_ * sizeof(float);
  constexpr size_t NEED = OFFP + (size_t)B_ * N_ * MCH * 5 * sizeof(float);
  if (ws_size < NEED) return;

  char* ws = (char*)d_ws;
  f16* XqH = (f16*)(ws);
  f16* XqL = XqH + SZX;
  f16* XkH = XqL + SZX;
  f16* XkL = XkH + SZX;
  f16* WqH = (f16*)(ws + OFFW);
  f16* WqL = WqH + (size_t)E_ * E_;
  f16* WkH = WqL + (size_t)E_ * E_;
  f16* WkL = WkH + (size_t)E_ * E_;
  f16* QH = (f16*)(ws + OFFQ);
  f16* QL = QH + SZX;
  f16* KH = QL + SZX;
  f16* KL = KH + SZX;
  float* kk = (float*)(ws + OFFK2);
  float* part = (float*)(ws + OFFP);

  k_split_w<<<dim3(E_ * E_ / 256), 256, 0, stream>>>(Wq, Wk, WqH, WqL, WkH, WkL);
  k_tsplit<<<dim3(E_ / 64, N_ / 64, B_ * 2), dim3(64, 4), 0, stream>>>(
      src_emb, tgt_emb, XqH, XqL, XkH, XkL);
  hipMemsetAsync(kk, 0, (size_t)B_ * M_ * sizeof(float), stream);
  k_proj<<<dim3(N_ / 128, E_ / 128, B_ * 2), 256, 0, stream>>>(
      XqH, XqL, XkH, XkL, WqH, WqL, WkH, WkL, bq, bk, QH, QL, KH, KL, kk);
  k_flash<<<dim3(N_ / 128, MCH, B_), 256, 0, stream>>>(QH, QL, KH, KL, kk, tgt, part);
  k_out<<<dim3(B_ * N_ / 256 + B_ * 3 * N_ / 256), 256, 0, stream>>>(part, src, out);
}

// Round 8
// 236.979 us; speedup vs baseline: 1.0465x; 1.0465x over previous
//
#include <hip/hip_runtime.h>

// VcpAtt: q = Wq@src_emb + bq ; k = Wk@tgt_emb + bk ;
// scores = softmax_m(2*q.k - ||k||^2)  (||q||^2 cancels in softmax)
// out = [src (copy), src_corr = tgt @ scores^T]
//
// fp16 hi/lo split (3-pass MFMA). Flash-fused S GEMM + online softmax + PV.
// R8: linear block mapping (R7 swizzle reverted — it destroyed Q L2-reuse);
// k_flash rebuilt: 8 waves x 16 rows, Q fragments in REGISTERS (loaded once,
// no A staging/restaging), K staged 3-buffered at prefetch depth 2 (vmcnt(4)).

typedef _Float16 f16;
typedef __attribute__((ext_vector_type(8))) _Float16 f16x8;
typedef __attribute__((ext_vector_type(4))) float f32x4;

constexpr int B_ = 2, E_ = 512, N_ = 4096, M_ = 4096;
constexpr int MCH = 8;               // m-chunks (512 cols each)
constexpr float WSCALE = 64.0f;

__device__ __forceinline__ f32x4 mfma16(f16x8 a, f16x8 b, f32x4 c) {
  return __builtin_amdgcn_mfma_f32_16x16x32_f16(a, b, c, 0, 0, 0);
}
__device__ __forceinline__ void gll16(const void* g, void* l) {
  __builtin_amdgcn_global_load_lds(
      (const __attribute__((address_space(1))) unsigned int*)g,
      (__attribute__((address_space(3))) unsigned int*)l, 16, 0, 0);
}
__device__ __forceinline__ void waitv8() { asm volatile("s_waitcnt vmcnt(8)" ::: "memory"); }
__device__ __forceinline__ void waitv4() { asm volatile("s_waitcnt vmcnt(4)" ::: "memory"); }
__device__ __forceinline__ void waitv2() { asm volatile("s_waitcnt vmcnt(2)" ::: "memory"); }
__device__ __forceinline__ void waitv0() { asm volatile("s_waitcnt vmcnt(0)" ::: "memory"); }
__device__ __forceinline__ f32x4 vmax4(f32x4 a, f32x4 b) {
  f32x4 r;
  r[0] = fmaxf(a[0], b[0]); r[1] = fmaxf(a[1], b[1]);
  r[2] = fmaxf(a[2], b[2]); r[3] = fmaxf(a[3], b[3]);
  return r;
}
__device__ __forceinline__ f32x4 vexp4(f32x4 a) {
  f32x4 r;
  r[0] = __expf(a[0]); r[1] = __expf(a[1]);
  r[2] = __expf(a[2]); r[3] = __expf(a[3]);
  return r;
}

// LDS K-tile: 128 rows x 128B. Row = 8 slots of 16B; logical slot q<4 = H
// elems [q*8,q*8+8) of the 32-wide K-block, q>=4 = L. Phys slot = q^(row&7).
// Staged linear-dest (global_load_lds) via inverse-swizzled global source.

// ---- split W into f16 hi/lo (scaled) ------------------------------------
__global__ void k_split_w(const float* __restrict__ Wq, const float* __restrict__ Wk,
                          f16* __restrict__ WqH, f16* __restrict__ WqL,
                          f16* __restrict__ WkH, f16* __restrict__ WkL) {
  int i = blockIdx.x * 256 + threadIdx.x;
  float a = Wq[i] * WSCALE;
  f16 ah = (f16)a; WqH[i] = ah; WqL[i] = (f16)(a - (float)ah);
  float b = Wk[i] * WSCALE;
  f16 bh = (f16)b; WkH[i] = bh; WkL[i] = (f16)(b - (float)bh);
}

// ---- transpose (E,N) fp32 -> (N,E) f16 hi/lo ----------------------------
__global__ void k_tsplit(const float* __restrict__ Xq, const float* __restrict__ Xk,
                         f16* __restrict__ XqH, f16* __restrict__ XqL,
                         f16* __restrict__ XkH, f16* __restrict__ XkL) {
  __shared__ float tile[64][65];
  const int b = blockIdx.z >> 1, which = blockIdx.z & 1;
  const float* X = (which ? Xk : Xq) + (size_t)b * E_ * N_;
  f16* H = (which ? XkH : XqH) + (size_t)b * N_ * E_;
  f16* L = (which ? XkL : XqL) + (size_t)b * N_ * E_;
  const int e0 = blockIdx.x * 64, n0 = blockIdx.y * 64;
  const int x = threadIdx.x, y = threadIdx.y;
#pragma unroll
  for (int j = 0; j < 16; ++j) {
    int e = y * 16 + j;
    tile[e][x] = X[(size_t)(e0 + e) * N_ + n0 + x];
  }
  __syncthreads();
#pragma unroll
  for (int j = 0; j < 16; ++j) {
    int nl = y * 16 + j;
    float v = tile[x][nl];
    f16 h = (f16)v;
    H[(size_t)(n0 + nl) * E_ + e0 + x] = h;
    L[(size_t)(n0 + nl) * E_ + e0 + x] = (f16)(v - (float)h);
  }
}

// ---- projection GEMM (pipelined 2x2-wave 128x128), kk fused -------------
__global__ __launch_bounds__(256, 2) void k_proj(
    const f16* __restrict__ XqH, const f16* __restrict__ XqL,
    const f16* __restrict__ XkH, const f16* __restrict__ XkL,
    const f16* __restrict__ WqH, const f16* __restrict__ WqL,
    const f16* __restrict__ WkH, const f16* __restrict__ WkL,
    const float* __restrict__ bq, const float* __restrict__ bk,
    f16* __restrict__ QH, f16* __restrict__ QL,
    f16* __restrict__ KH, f16* __restrict__ KL,
    float* __restrict__ kkout) {
  __shared__ char lds[65536];   // A:[2]x16K @0, B:[2]x16K @32768
  const int b = blockIdx.z >> 1, kind = blockIdx.z & 1;
  const f16* AH = (kind ? XkH : XqH) + (size_t)b * N_ * E_;
  const f16* AL = (kind ? XkL : XqL) + (size_t)b * N_ * E_;
  const f16* BH = kind ? WkH : WqH;
  const f16* BL = kind ? WkL : WqL;
  const float* bias = kind ? bk : bq;
  f16* OH = (kind ? KH : QH) + (size_t)b * N_ * E_;
  f16* OL = (kind ? KL : QL) + (size_t)b * N_ * E_;
  const int n0 = blockIdx.x * 128, f0 = blockIdx.y * 128;
  const int l = threadIdx.x & 63, w = threadIdx.x >> 6;
  const int wr = (w >> 1) * 64, wc = (w & 1) * 64;
  const int r15 = l & 15;

  const int q = (l & 7) ^ (l >> 3);
  const size_t soff = (size_t)(w * 8 + (l >> 3)) * E_ + (q & 3) * 8;
  const f16* sA = (q < 4 ? AH : AL) + (size_t)n0 * E_ + soff;
  const f16* sB = (q < 4 ? BH : BL) + (size_t)f0 * E_ + soff;

  auto STAGE = [&](int k) {
    char* dA = lds + ((k & 1) << 14) + w * 1024;
    char* dB = lds + 32768 + ((k & 1) << 14) + w * 1024;
    const f16* pa = sA + k * 32;
    const f16* pb = sB + k * 32;
#pragma unroll
    for (int c = 0; c < 4; ++c) {
      gll16(pa + (size_t)c * 32 * E_, dA + c * 4096);
      gll16(pb + (size_t)c * 32 * E_, dB + c * 4096);
    }
  };

  const int pH16 = ((l >> 4) ^ (l & 7)) * 16;
  const int aoffH = (wr + r15) * 128 + pH16;
  const int boffH = (wc + r15) * 128 + pH16;

  f32x4 acc[4][4] = {};
  STAGE(0);
#pragma unroll 2
  for (int k = 0; k < 16; ++k) {
    if (k < 15) { STAGE(k + 1); waitv8(); } else { waitv0(); }
    __builtin_amdgcn_sched_barrier(0);
    __builtin_amdgcn_s_barrier();
    const char* cA = lds + ((k & 1) << 14);
    const char* cB = lds + 32768 + ((k & 1) << 14);
    f16x8 ah[4], al[4], bh[4], bl[4];
#pragma unroll
    for (int i = 0; i < 4; ++i) {
      ah[i] = *(const f16x8*)(cA + aoffH + i * 2048);
      al[i] = *(const f16x8*)(cA + (aoffH ^ 64) + i * 2048);
      bh[i] = *(const f16x8*)(cB + boffH + i * 2048);
      bl[i] = *(const f16x8*)(cB + (boffH ^ 64) + i * 2048);
    }
    __builtin_amdgcn_s_setprio(1);
#pragma unroll
    for (int i = 0; i < 4; ++i)
#pragma unroll
      for (int j = 0; j < 4; ++j) {
        acc[i][j] = mfma16(ah[i], bh[j], acc[i][j]);
        acc[i][j] = mfma16(ah[i], bl[j], acc[i][j]);
        acc[i][j] = mfma16(al[i], bh[j], acc[i][j]);
      }
    __builtin_amdgcn_s_setprio(0);
    __builtin_amdgcn_s_barrier();
  }

  const int rowg = (l >> 4) * 4;
  float kkp[4][4];
#pragma unroll
  for (int i = 0; i < 4; ++i)
#pragma unroll
    for (int r = 0; r < 4; ++r) kkp[i][r] = 0.f;
#pragma unroll
  for (int j = 0; j < 4; ++j) {
    int f = f0 + wc + j * 16 + r15;
    float bv = bias[f];
#pragma unroll
    for (int i = 0; i < 4; ++i) {
#pragma unroll
      for (int r = 0; r < 4; ++r) {
        int n = n0 + wr + i * 16 + rowg + r;
        float qv = acc[i][j][r] * (1.0f / WSCALE) + bv;
        f16 h = (f16)qv;
        OH[(size_t)n * E_ + f] = h;
        OL[(size_t)n * E_ + f] = (f16)(qv - (float)h);
        kkp[i][r] += qv * qv;
      }
    }
  }
  if (kind) {
#pragma unroll
    for (int i = 0; i < 4; ++i)
#pragma unroll
      for (int r = 0; r < 4; ++r) {
        float v = kkp[i][r];
        v += __shfl_xor(v, 1); v += __shfl_xor(v, 2);
        v += __shfl_xor(v, 4); v += __shfl_xor(v, 8);
        if (r15 == 0) {
          int n = n0 + wr + i * 16 + rowg + r;
          atomicAdd(&kkout[(size_t)b * M_ + n], v);
        }
      }
  }
}

// ---- flash: Q-in-registers, K 3-buffered depth-2, online softmax + PV ---
// grid (32, MCH, B) linear; 512 threads = 8 waves x 16 rows.
__global__ __launch_bounds__(512, 2) void k_flash(
    const f16* __restrict__ QH, const f16* __restrict__ QL,
    const f16* __restrict__ KH, const f16* __restrict__ KL,
    const float* __restrict__ kk, const float* __restrict__ tgt,
    float* __restrict__ part) {
  __shared__ char lds[57344];          // K: 3 x 16KB @0; ksw @49152 (8KB)
  float* ksw = (float*)(lds + 49152);  // [4][16][8] x {kk,t0,t1,t2}
  const int b = blockIdx.z;
  const int n0 = blockIdx.x * 128;
  const int mc = blockIdx.y, m0c = mc * 512;
  const int tid = threadIdx.x, l = tid & 63, w = tid >> 6;
  const int r15 = l & 15, hi = l >> 4;

  // kk/tgt -> LDS, swizzled per-lane-contiguous
  {
    int idx = tid;
    int mt = idx >> 7, rem = idx & 127, j = rem >> 4, rr = rem & 15;
    int dst = (mt * 16 + rr) * 8 + j;
    ksw[dst]        = kk[(size_t)b * M_ + m0c + idx];
    ksw[512 + dst]  = tgt[((size_t)b * 3 + 0) * M_ + m0c + idx];
    ksw[1024 + dst] = tgt[((size_t)b * 3 + 1) * M_ + m0c + idx];
    ksw[1536 + dst] = tgt[((size_t)b * 3 + 2) * M_ + m0c + idx];
  }
  __syncthreads();   // ksw visible before any use (also before load issues)

  // ---- Q fragments -> registers (once; Q never restaged) ----
  const size_t arow = ((size_t)b * N_ + n0 + w * 16 + r15) * E_ + hi * 8;
  const f16* Agh = QH + arow;
  const f16* Agl = QL + arow;
  f16x8 ah[16], al[16];
#pragma unroll
  for (int k = 0; k < 16; ++k) {
    ah[k] = *(const f16x8*)(Agh + k * 32);
    al[k] = *(const f16x8*)(Agl + k * 32);
  }

  // ---- K staging setup: thread covers 2x16B per step ----
  const int qq = (tid & 7) ^ ((tid >> 3) & 7);
  const f16* KHb = KH + ((size_t)b * M_ + m0c) * E_;
  const f16* KLb = KL + ((size_t)b * M_ + m0c) * E_;
  const f16* sBr = (qq < 4 ? KHb : KLb) + (size_t)(tid >> 3) * E_ + (qq & 3) * 8;

  auto STAGE = [&](int s) {   // s is compile-time constant after unroll
    char* d = lds + (s % 3) * 16384 + tid * 16;
    const f16* p = sBr + (size_t)((s >> 4) * 128) * E_ + (s & 15) * 32;
    gll16(p, d);
    gll16(p + (size_t)64 * E_, d + 8192);
  };

  const int boffH = r15 * 128 + ((hi ^ (l & 7)) * 16);

  f32x4 acc[8];
  f32x4 mrun = {-3.0e38f, -3.0e38f, -3.0e38f, -3.0e38f};
  f32x4 psum = {}, p0 = {}, p1 = {}, p2 = {};

  STAGE(0);
  STAGE(1);

#pragma unroll
  for (int mt = 0; mt < 4; ++mt) {
#pragma unroll
    for (int j = 0; j < 8; ++j) acc[j] = f32x4{0.f, 0.f, 0.f, 0.f};
#pragma unroll
    for (int k = 0; k < 16; ++k) {
      const int s = mt * 16 + k;
      if (s < 62) { STAGE(s + 2); waitv4(); }
      else if (s == 62) waitv2();
      else waitv0();
      __builtin_amdgcn_sched_barrier(0);
      __builtin_amdgcn_s_barrier();
      const char* cB = lds + (s % 3) * 16384;
      __builtin_amdgcn_s_setprio(1);
#pragma unroll
      for (int j = 0; j < 8; ++j) {
        f16x8 bh = *(const f16x8*)(cB + boffH + j * 2048);
        f16x8 bl = *(const f16x8*)(cB + (boffH ^ 64) + j * 2048);
        acc[j] = mfma16(ah[k], bh, acc[j]);
        acc[j] = mfma16(ah[k], bl, acc[j]);
        acc[j] = mfma16(al[k], bh, acc[j]);
      }
      __builtin_amdgcn_s_setprio(0);
      __builtin_amdgcn_s_barrier();
    }

    // ---- online softmax + PV for this m-tile (register-local) ----
    {
      const float* bp = ksw + (mt * 16 + r15) * 8;
      float kv[8], tv0[8], tv1[8], tv2[8];
#pragma unroll
      for (int j = 0; j < 8; ++j) {
        kv[j] = bp[j];
        tv0[j] = bp[512 + j];
        tv1[j] = bp[1024 + j];
        tv2[j] = bp[1536 + j];
      }
      f32x4 mx = {-3.0e38f, -3.0e38f, -3.0e38f, -3.0e38f};
#pragma unroll
      for (int j = 0; j < 8; ++j) mx = vmax4(mx, 2.0f * acc[j] - kv[j]);
#pragma unroll
      for (int e = 0; e < 4; ++e) {
        float v = mx[e];
        v = fmaxf(v, __shfl_xor(v, 1)); v = fmaxf(v, __shfl_xor(v, 2));
        v = fmaxf(v, __shfl_xor(v, 4)); v = fmaxf(v, __shfl_xor(v, 8));
        mx[e] = v;
      }
      f32x4 nm = vmax4(mrun, mx);
      f32x4 sc = vexp4(mrun - nm);
      mrun = nm;
      psum *= sc; p0 *= sc; p1 *= sc; p2 *= sc;
#pragma unroll
      for (int j = 0; j < 8; ++j) {
        f32x4 e4 = vexp4(2.0f * acc[j] - kv[j] - nm);
        psum += e4;
        p0 += e4 * tv0[j];
        p1 += e4 * tv1[j];
        p2 += e4 * tv2[j];
      }
    }
  }

  // reduce across the 16-lane m-groups, write per-chunk partials
  auto RED = [&](f32x4& v) __attribute__((always_inline)) {
#pragma unroll
    for (int e = 0; e < 4; ++e) {
      float x = v[e];
      x += __shfl_xor(x, 1); x += __shfl_xor(x, 2);
      x += __shfl_xor(x, 4); x += __shfl_xor(x, 8);
      v[e] = x;
    }
  };
  RED(psum); RED(p0); RED(p1); RED(p2);

  if (r15 == 0) {
#pragma unroll
    for (int r = 0; r < 4; ++r) {
      int n = n0 + w * 16 + hi * 4 + r;
      size_t pb = ((size_t)(b * N_ + n) * MCH + mc) * 5;
      part[pb + 0] = mrun[r];
      part[pb + 1] = psum[r];
      part[pb + 2] = p0[r];
      part[pb + 3] = p1[r];
      part[pb + 4] = p2[r];
    }
  }
}

// ---- combine per-chunk partials -> output, plus src passthrough ---------
__global__ void k_out(const float* __restrict__ part, const float* __restrict__ src,
                      float* __restrict__ out) {
  int gid = blockIdx.x * 256 + threadIdx.x;
  if (blockIdx.x < B_ * N_ / 256) {           // combine: 8192 rows
    int idx = gid;                            // b*N + n
    int b = idx >> 12, n = idx & (N_ - 1);
    const float* p = part + (size_t)idx * MCH * 5;
    float M = -3.0e38f;
#pragma unroll
    for (int c = 0; c < MCH; ++c) M = fmaxf(M, p[c * 5]);
    float S = 0.f, P0 = 0.f, P1 = 0.f, P2 = 0.f;
#pragma unroll
    for (int c = 0; c < MCH; ++c) {
      float e = __expf(p[c * 5] - M);
      S += p[c * 5 + 1] * e;
      P0 += p[c * 5 + 2] * e;
      P1 += p[c * 5 + 3] * e;
      P2 += p[c * 5 + 4] * e;
    }
    float inv = 1.0f / S;
    float* oc = out + (size_t)B_ * 3 * N_;
    oc[((size_t)b * 3 + 0) * N_ + n] = P0 * inv;
    oc[((size_t)b * 3 + 1) * N_ + n] = P1 * inv;
    oc[((size_t)b * 3 + 2) * N_ + n] = P2 * inv;
  } else {                                    // src copy: 24576 elements
    int i = gid - B_ * N_;
    out[i] = src[i];
  }
}

extern "C" void kernel_launch(void* const* d_in, const int* in_sizes, int n_in,
                              void* d_out, int out_size, void* d_ws, size_t ws_size,
                              hipStream_t stream) {
  const float* src_emb = (const float*)d_in[0];
  const float* tgt_emb = (const float*)d_in[1];
  const float* src     = (const float*)d_in[2];
  const float* tgt     = (const float*)d_in[3];
  const float* Wq      = (const float*)d_in[4];
  const float* bq      = (const float*)d_in[5];
  const float* Wk      = (const float*)d_in[6];
  const float* bk      = (const float*)d_in[7];
  float* out = (float*)d_out;

  constexpr size_t SZX = (size_t)B_ * N_ * E_;
  constexpr size_t OFFW = 4 * SZX * sizeof(f16);
  constexpr size_t OFFQ = OFFW + 4 * (size_t)E_ * E_ * sizeof(f16);
  constexpr size_t OFFK2 = OFFQ + 4 * SZX * sizeof(f16);
  constexpr size_t OFFP = OFFK2 + (size_t)B_ * M_ * sizeof(float);
  constexpr size_t NEED = OFFP + (size_t)B_ * N_ * MCH * 5 * sizeof(float);
  if (ws_size < NEED) return;

  char* ws = (char*)d_ws;
  f16* XqH = (f16*)(ws);
  f16* XqL = XqH + SZX;
  f16* XkH = XqL + SZX;
  f16* XkL = XkH + SZX;
  f16* WqH = (f16*)(ws + OFFW);
  f16* WqL = WqH + (size_t)E_ * E_;
  f16* WkH = WqL + (size_t)E_ * E_;
  f16* WkL = WkH + (size_t)E_ * E_;
  f16* QH = (f16*)(ws + OFFQ);
  f16* QL = QH + SZX;
  f16* KH = QL + SZX;
  f16* KL = KH + SZX;
  float* kk = (float*)(ws + OFFK2);
  float* part = (float*)(ws + OFFP);

  k_split_w<<<dim3(E_ * E_ / 256), 256, 0, stream>>>(Wq, Wk, WqH, WqL, WkH, WkL);
  k_tsplit<<<dim3(E_ / 64, N_ / 64, B_ * 2), dim3(64, 4), 0, stream>>>(
      src_emb, tgt_emb, XqH, XqL, XkH, XkL);
  hipMemsetAsync(kk, 0, (size_t)B_ * M_ * sizeof(float), stream);
  k_proj<<<dim3(N_ / 128, E_ / 128, B_ * 2), 256, 0, stream>>>(
      XqH, XqL, XkH, XkL, WqH, WqL, WkH, WkL, bq, bk, QH, QL, KH, KL, kk);
  k_flash<<<dim3(N_ / 128, MCH, B_), 512, 0, stream>>>(QH, QL, KH, KL, kk, tgt, part);
  k_out<<<dim3(B_ * N_ / 256 + B_ * 3 * N_ / 256), 256, 0, stream>>>(part, src, out);
}